// Round 1
// baseline (1422.839 us; speedup 1.0000x reference)
//
#include <hip/hip_runtime.h>

// Viterbi decode (LinearCRF): features [B,S,L] f32, transitions [L,L] f32 -> best_path [B,S] int32
// B=512, S=1024, L=64. One wave (64 lanes) per batch element; lane = tag j.
constexpr int Bn = 512;
constexpr int Sn = 1024;
constexpr int Ln = 64;

// ---- wave64 max reduction via DPP (VALU-speed, no LDS latency) ----
#define DPPMAX(ctrl)                                                          \
  {                                                                           \
    int _xi = __float_as_int(x);                                              \
    int _yi = __builtin_amdgcn_update_dpp(_xi, _xi, ctrl, 0xf, 0xf, false);   \
    x = fmaxf(x, __int_as_float(_yi));                                        \
  }

__device__ __forceinline__ float wave_max64(float x) {
  DPPMAX(0x121)  // row_ror:1
  DPPMAX(0x122)  // row_ror:2
  DPPMAX(0x124)  // row_ror:4
  DPPMAX(0x128)  // row_ror:8  -> every lane holds its 16-lane row max
  DPPMAX(0x142)  // row_bcast15
  DPPMAX(0x143)  // row_bcast31 -> lane 63 holds wave max
  return __int_as_float(__builtin_amdgcn_readlane(__float_as_int(x), 63));
}

__global__ __launch_bounds__(64) void crf_forward(
    const float* __restrict__ feat,       // [B][S][L]
    const float* __restrict__ Tm,         // [L][L]
    unsigned char* __restrict__ bp,       // [B][S-1][L] backpointers (slow steps only)
    unsigned char* __restrict__ coal,     // [B][S] : istar if step coalesced, else 0xFF
    int* __restrict__ last_tag)           // [B]
{
  const int b = blockIdx.x;
  const int j = threadIdx.x;  // tag index 0..63

  __shared__ __align__(16) float sT[Ln * Ln];  // transitions row-major
  __shared__ __align__(16) float sfv[Ln];      // forward_var broadcast buffer

  // tcol[i] = T[i][j] : lane j holds column j of T in registers (static indexing only)
  float tcol[Ln];
#pragma unroll
  for (int i = 0; i < Ln; ++i) {
    float v = Tm[i * Ln + j];
    tcol[i] = v;
    sT[i * Ln + j] = v;
  }
  __syncthreads();

  // span of T = maxT - minT (wave-uniform), for the single-candidate test
  float tmx = tcol[0], tmn = tcol[0];
#pragma unroll
  for (int i = 1; i < Ln; ++i) {
    tmx = fmaxf(tmx, tcol[i]);
    tmn = fminf(tmn, tcol[i]);
  }
#pragma unroll
  for (int off = 32; off >= 1; off >>= 1) {
    tmx = fmaxf(tmx, __shfl_xor(tmx, off));
    tmn = fminf(tmn, __shfl_xor(tmn, off));
  }
  const float Dspan = tmx - tmn;

  const float* fb = feat + ((size_t)b * Sn) * Ln + j;
  unsigned char* bpb = bp + ((size_t)b * (Sn - 1)) * Ln + j;
  unsigned char* coalb = coal + (size_t)b * Sn;

  // forward_var = features[b][0][:]; software prefetch features 3 steps ahead
  float fv = fb[0];
  float p1 = fb[(size_t)1 * Ln];
  float p2 = fb[(size_t)2 * Ln];
  float p3 = fb[(size_t)3 * Ln];

  for (int t = 1; t < Sn; ++t) {
    const float featc = p1;
    p1 = p2;
    p2 = p3;
    const int tn = (t + 3 < Sn) ? (t + 3) : (Sn - 1);
    p3 = fb[(size_t)tn * Ln];

    // publish fv for (possible) slow-path broadcast reads
    sfv[j] = fv;
    asm volatile("s_waitcnt lgkmcnt(0)" ::: "memory");

    const float M = wave_max64(fv);
    // candidate threshold: only i with fv_i >= M - Dspan - eps can win ANY column.
    // eps covers fp rounding of the score adds (scores ~ |M|), conservatively.
    const float eps = fabsf(M) * 4e-6f + 1e-4f;
    const float thr = (M - Dspan) - eps;
    const unsigned long long cmask = __ballot(fv >= thr);

    unsigned char cv;
    if (__popcll(cmask) == 1) {
      // ---- fast path: unique candidate i* wins every column (provable margin) ----
      const int istar = __ffsll((long long)cmask) - 1;
      const float trow = sT[istar * Ln + j];  // consecutive addresses, conflict-free
      fv = featc + (M + trow);                // rnd(feat + rnd(fv[i*] + T[i*][j])) == reference
      cv = (unsigned char)istar;              // coalesced: path[t-1] = i* unconditionally
    } else {
      // ---- slow path: full argmax over 64 predecessors, first-index-wins ----
      float v32[32];
      int x32[32];
#pragma unroll
      for (int i0 = 0; i0 < Ln; i0 += 4) {
        const float4 q = *(const float4*)(sfv + i0);  // uniform-address broadcast read
        const float a = q.x + tcol[i0 + 0];
        const float bb = q.y + tcol[i0 + 1];
        const float c = q.z + tcol[i0 + 2];
        const float d = q.w + tcol[i0 + 3];
        v32[i0 / 2] = fmaxf(a, bb);
        x32[i0 / 2] = (bb > a) ? (i0 + 1) : i0;         // strict > keeps lower index on tie
        v32[i0 / 2 + 1] = fmaxf(c, d);
        x32[i0 / 2 + 1] = (d > c) ? (i0 + 3) : (i0 + 2);
      }
      float v16[16];
      int x16[16];
#pragma unroll
      for (int i = 0; i < 16; ++i) {
        const bool tk = v32[2 * i + 1] > v32[2 * i];
        v16[i] = fmaxf(v32[2 * i], v32[2 * i + 1]);
        x16[i] = tk ? x32[2 * i + 1] : x32[2 * i];
      }
      float v8[8];
      int x8[8];
#pragma unroll
      for (int i = 0; i < 8; ++i) {
        const bool tk = v16[2 * i + 1] > v16[2 * i];
        v8[i] = fmaxf(v16[2 * i], v16[2 * i + 1]);
        x8[i] = tk ? x16[2 * i + 1] : x16[2 * i];
      }
      float v4[4];
      int x4[4];
#pragma unroll
      for (int i = 0; i < 4; ++i) {
        const bool tk = v8[2 * i + 1] > v8[2 * i];
        v4[i] = fmaxf(v8[2 * i], v8[2 * i + 1]);
        x4[i] = tk ? x8[2 * i + 1] : x8[2 * i];
      }
      const bool tk2a = v4[1] > v4[0];
      const float v2a = fmaxf(v4[0], v4[1]);
      const int x2a = tk2a ? x4[1] : x4[0];
      const bool tk2b = v4[3] > v4[2];
      const float v2b = fmaxf(v4[2], v4[3]);
      const int x2b = tk2b ? x4[3] : x4[2];
      const bool tkf = v2b > v2a;
      const float vbest = fmaxf(v2a, v2b);
      const int xbest = tkf ? x2b : x2a;

      fv = featc + vbest;
      bpb[(size_t)(t - 1) * Ln] = (unsigned char)xbest;
      // detect coalescence even on slow path (helps backtrace segmenting)
      const int f0 = __builtin_amdgcn_readfirstlane(xbest);
      cv = (__ballot(xbest == f0) == ~0ull) ? (unsigned char)f0 : (unsigned char)0xFF;
    }
    if (j == 0) coalb[t] = cv;
  }

  // last_tag = first-index argmax of final forward_var
  const float Mf = wave_max64(fv);
  const unsigned long long mk = __ballot(fv == Mf);
  if (j == 0) last_tag[b] = __ffsll((long long)mk) - 1;
}

__global__ __launch_bounds__(256) void crf_backtrace(
    const unsigned char* __restrict__ bp, const unsigned char* __restrict__ coal,
    const int* __restrict__ last_tag, int* __restrict__ out)
{
  const int gid = blockIdx.x * blockDim.x + threadIdx.x;
  if (gid >= Bn * Sn) return;
  const int b = gid >> 10;       // / Sn
  const int t = gid & (Sn - 1);  // % Sn

  const unsigned char* cb = coal + (size_t)b * Sn;
  int tag = -1;
  int u = t;
  // walk forward to the nearest chain break (coalesced step or sequence end)
  while (u < Sn - 1) {
    const unsigned char c = cb[u + 1];
    if (c != 0xFF) { tag = c; break; }  // path[u] = istar of step u+1
    ++u;
  }
  if (u == Sn - 1) tag = last_tag[b];
  // walk back through non-coalesced steps applying stored backpointers
  const unsigned char* bpb = bp + (size_t)b * (Sn - 1) * Ln;
  for (; u > t; --u) tag = bpb[(size_t)(u - 1) * Ln + tag];
  out[gid] = tag;
}

extern "C" void kernel_launch(void* const* d_in, const int* in_sizes, int n_in,
                              void* d_out, int out_size, void* d_ws, size_t ws_size,
                              hipStream_t stream) {
  const float* feat = (const float*)d_in[0];
  const float* Tm = (const float*)d_in[1];

  // workspace layout: bp | coal | last_tag   (~34 MB total)
  unsigned char* bp = (unsigned char*)d_ws;
  const size_t bp_sz = (size_t)Bn * (Sn - 1) * Ln;  // 33,521,664
  unsigned char* coal = bp + bp_sz;
  const size_t coal_sz = (size_t)Bn * Sn;           // 524,288
  int* last_tag = (int*)(coal + coal_sz);

  int* out = (int*)d_out;

  crf_forward<<<Bn, 64, 0, stream>>>(feat, Tm, bp, coal, last_tag);
  const int total = Bn * Sn;
  crf_backtrace<<<(total + 255) / 256, 256, 0, stream>>>(bp, coal, last_tag, out);
}

// Round 2
// 375.470 us; speedup vs baseline: 3.7895x; 3.7895x over previous
//
#include <hip/hip_runtime.h>

// Viterbi decode (LinearCRF): features [B,S,L] f32, transitions [L,L] f32 -> best_path [B,S] int32
// B=512, S=1024, L=64. One wave (64 lanes) per batch element; lane = tag j.
constexpr int Bn = 512;
constexpr int Sn = 1024;
constexpr int Ln = 64;

// ---- wave64 max reduction via DPP (VALU-speed) ----
#define DPPMAX(ctrl)                                                          \
  {                                                                           \
    int _xi = __float_as_int(x);                                              \
    int _yi = __builtin_amdgcn_update_dpp(_xi, _xi, ctrl, 0xf, 0xf, false);   \
    x = fmaxf(x, __int_as_float(_yi));                                        \
  }

__device__ __forceinline__ float wave_max64(float x) {
  DPPMAX(0x121)  // row_ror:1
  DPPMAX(0x122)  // row_ror:2
  DPPMAX(0x124)  // row_ror:4
  DPPMAX(0x128)  // row_ror:8
  DPPMAX(0x142)  // row_bcast15
  DPPMAX(0x143)  // row_bcast31 -> lane 63 holds wave max
  return __int_as_float(__builtin_amdgcn_readlane(__float_as_int(x), 63));
}

__device__ __forceinline__ float rdlane(float v, int lane) {
  return __int_as_float(__builtin_amdgcn_readlane(__float_as_int(v), lane));
}

// One Viterbi step. Uses from scope: fv, Dspan, sT, j, bpb, coalb.
// Exact-arithmetic: all adds are rnd(fv_i + T[i][j]) then rnd(feat + best),
// selection is strict-> in increasing index order == np.argmax first-index rule.
#define CRF_STEP(T_, FEATC_)                                                               \
  do {                                                                                     \
    const float M_ = wave_max64(fv);                                                       \
    const float thr_ = (M_ - Dspan) - (fabsf(M_) * 4e-6f + 1e-4f);                         \
    const unsigned long long cm_ = __ballot(fv >= thr_);                                   \
    const int k_ = __popcll(cm_);                                                          \
    unsigned char cv_;                                                                     \
    if (k_ <= 4) {                                                                         \
      unsigned long long m_ = cm_;                                                         \
      const int i0_ = __ffsll((long long)m_) - 1; m_ &= m_ - 1;                            \
      const int i1_ = (k_ > 1) ? __ffsll((long long)m_) - 1 : i0_; m_ &= m_ - 1;           \
      const int i2_ = (k_ > 2) ? __ffsll((long long)m_) - 1 : i0_; m_ &= m_ - 1;           \
      const int i3_ = (k_ > 3) ? __ffsll((long long)m_) - 1 : i0_;                         \
      const float t0_ = sT[i0_ * Ln + j];                                                  \
      const float t1_ = sT[i1_ * Ln + j];                                                  \
      const float t2_ = sT[i2_ * Ln + j];                                                  \
      const float t3_ = sT[i3_ * Ln + j];                                                  \
      const float v0_ = rdlane(fv, i0_);                                                   \
      const float v1_ = rdlane(fv, i1_);                                                   \
      const float v2_ = rdlane(fv, i2_);                                                   \
      const float v3_ = rdlane(fv, i3_);                                                   \
      float best_ = v0_ + t0_; int bx_ = i0_;                                              \
      { const float s_ = v1_ + t1_; const bool tk_ = (k_ > 1) && (s_ > best_);             \
        best_ = tk_ ? s_ : best_; bx_ = tk_ ? i1_ : bx_; }                                 \
      { const float s_ = v2_ + t2_; const bool tk_ = (k_ > 2) && (s_ > best_);             \
        best_ = tk_ ? s_ : best_; bx_ = tk_ ? i2_ : bx_; }                                 \
      { const float s_ = v3_ + t3_; const bool tk_ = (k_ > 3) && (s_ > best_);             \
        best_ = tk_ ? s_ : best_; bx_ = tk_ ? i3_ : bx_; }                                 \
      fv = (FEATC_) + best_;                                                               \
      if (k_ == 1) {                                                                       \
        cv_ = (unsigned char)i0_;                                                          \
      } else {                                                                             \
        bpb[(size_t)((T_) - 1) * Ln] = (unsigned char)bx_;                                 \
        const int f0_ = __builtin_amdgcn_readfirstlane(bx_);                               \
        cv_ = (__ballot(bx_ == f0_) == ~0ull) ? (unsigned char)f0_ : (unsigned char)0xFF;  \
      }                                                                                    \
    } else {                                                                               \
      /* full 64-way argmax: 4-class running scan, first-index-correct fold */             \
      float bv0_, bv1_, bv2_, bv3_;                                                        \
      int bx0_, bx1_, bx2_, bx3_;                                                          \
      _Pragma("unroll")                                                                    \
      for (int i0 = 0; i0 < Ln; i0 += 4) {                                                 \
        const float fa_ = rdlane(fv, i0 + 0);                                              \
        const float fb2_ = rdlane(fv, i0 + 1);                                             \
        const float fc_ = rdlane(fv, i0 + 2);                                              \
        const float fd_ = rdlane(fv, i0 + 3);                                              \
        const float sa_ = fa_ + sT[(i0 + 0) * Ln + j];                                     \
        const float sb_ = fb2_ + sT[(i0 + 1) * Ln + j];                                    \
        const float sc_ = fc_ + sT[(i0 + 2) * Ln + j];                                     \
        const float sd_ = fd_ + sT[(i0 + 3) * Ln + j];                                     \
        if (i0 == 0) {                                                                     \
          bv0_ = sa_; bx0_ = 0; bv1_ = sb_; bx1_ = 1;                                      \
          bv2_ = sc_; bx2_ = 2; bv3_ = sd_; bx3_ = 3;                                      \
        } else {                                                                           \
          { const bool tk_ = sa_ > bv0_; bv0_ = fmaxf(bv0_, sa_); bx0_ = tk_ ? i0 + 0 : bx0_; } \
          { const bool tk_ = sb_ > bv1_; bv1_ = fmaxf(bv1_, sb_); bx1_ = tk_ ? i0 + 1 : bx1_; } \
          { const bool tk_ = sc_ > bv2_; bv2_ = fmaxf(bv2_, sc_); bx2_ = tk_ ? i0 + 2 : bx2_; } \
          { const bool tk_ = sd_ > bv3_; bv3_ = fmaxf(bv3_, sd_); bx3_ = tk_ ? i0 + 3 : bx3_; } \
        }                                                                                  \
      }                                                                                    \
      float best_ = bv0_; int bx_ = bx0_;                                                  \
      { const bool tk_ = (bv1_ > best_) || ((bv1_ == best_) && (bx1_ < bx_));              \
        best_ = tk_ ? bv1_ : best_; bx_ = tk_ ? bx1_ : bx_; }                              \
      { const bool tk_ = (bv2_ > best_) || ((bv2_ == best_) && (bx2_ < bx_));              \
        best_ = tk_ ? bv2_ : best_; bx_ = tk_ ? bx2_ : bx_; }                              \
      { const bool tk_ = (bv3_ > best_) || ((bv3_ == best_) && (bx3_ < bx_));              \
        best_ = tk_ ? bv3_ : best_; bx_ = tk_ ? bx3_ : bx_; }                              \
      fv = (FEATC_) + best_;                                                               \
      bpb[(size_t)((T_) - 1) * Ln] = (unsigned char)bx_;                                   \
      const int f0_ = __builtin_amdgcn_readfirstlane(bx_);                                 \
      cv_ = (__ballot(bx_ == f0_) == ~0ull) ? (unsigned char)f0_ : (unsigned char)0xFF;    \
    }                                                                                      \
    if (j == 0) coalb[(T_)] = cv_;                                                         \
  } while (0)

__global__ __launch_bounds__(64) void crf_forward(
    const float* __restrict__ feat,       // [B][S][L]
    const float* __restrict__ Tm,         // [L][L]
    unsigned char* __restrict__ bp,       // [B][S-1][L] backpointers (non-unique steps)
    unsigned char* __restrict__ coal,     // [B][S] : istar if step coalesced, else 0xFF
    int* __restrict__ last_tag)           // [B]
{
  const int b = blockIdx.x;
  const int j = threadIdx.x;  // tag index 0..63

  __shared__ __align__(16) float sT[Ln * Ln];  // transitions row-major

  // stage T, tracking global span (no per-lane T column kept in registers!)
  float tmx = -1e30f, tmn = 1e30f;
#pragma unroll 8
  for (int i = 0; i < Ln; ++i) {
    const float v = Tm[i * Ln + j];
    sT[i * Ln + j] = v;
    tmx = fmaxf(tmx, v);
    tmn = fminf(tmn, v);
  }
  __syncthreads();
#pragma unroll
  for (int off = 32; off >= 1; off >>= 1) {
    tmx = fmaxf(tmx, __shfl_xor(tmx, off));
    tmn = fminf(tmn, __shfl_xor(tmn, off));
  }
  const float Dspan = tmx - tmn;

  const float* fb = feat + ((size_t)b * Sn) * Ln + j;
  unsigned char* bpb = bp + ((size_t)b * (Sn - 1)) * Ln + j;
  unsigned char* coalb = coal + (size_t)b * Sn;

  // forward_var = features[b][0][:]; 8-deep software prefetch ring (static indices)
  float fv = fb[0];
  float pf[8];
#pragma unroll
  for (int u = 0; u < 8; ++u) pf[u] = fb[(size_t)(1 + u) * Ln];

  // main loop: t = 1 .. 1016 in blocks of 8; pf[u] consumed 8 steps after issue
  for (int tb = 1; tb <= Sn - 8; tb += 8) {
#pragma unroll
    for (int u = 0; u < 8; ++u) {
      const int t = tb + u;
      const float featc = pf[u];
      int tn = t + 8;
      if (tn > Sn - 1) tn = Sn - 1;
      pf[u] = fb[(size_t)tn * Ln];
      CRF_STEP(t, featc);
    }
  }
  // tail: t = 1017 .. 1023 (pf[0..6] hold those features)
#pragma unroll
  for (int u = 0; u < 7; ++u) {
    const float featc = pf[u];
    CRF_STEP(1017 + u, featc);
  }

  // last_tag = first-index argmax of final forward_var
  const float Mf = wave_max64(fv);
  const unsigned long long mk = __ballot(fv == Mf);
  if (j == 0) last_tag[b] = __ffsll((long long)mk) - 1;
}

__global__ __launch_bounds__(256) void crf_backtrace(
    const unsigned char* __restrict__ bp, const unsigned char* __restrict__ coal,
    const int* __restrict__ last_tag, int* __restrict__ out)
{
  const int gid = blockIdx.x * blockDim.x + threadIdx.x;
  if (gid >= Bn * Sn) return;
  const int b = gid >> 10;       // / Sn
  const int t = gid & (Sn - 1);  // % Sn

  const unsigned char* cb = coal + (size_t)b * Sn;
  int tag = -1;
  int u = t;
  // walk forward to the nearest chain break (coalesced step or sequence end)
  while (u < Sn - 1) {
    const unsigned char c = cb[u + 1];
    if (c != 0xFF) { tag = c; break; }  // path[u] = istar of step u+1
    ++u;
  }
  if (u == Sn - 1) tag = last_tag[b];
  // walk back through non-coalesced steps applying stored backpointers
  const unsigned char* bpb = bp + (size_t)b * (Sn - 1) * Ln;
  for (; u > t; --u) tag = bpb[(size_t)(u - 1) * Ln + tag];
  out[gid] = tag;
}

extern "C" void kernel_launch(void* const* d_in, const int* in_sizes, int n_in,
                              void* d_out, int out_size, void* d_ws, size_t ws_size,
                              hipStream_t stream) {
  const float* feat = (const float*)d_in[0];
  const float* Tm = (const float*)d_in[1];

  // workspace layout: bp | coal | last_tag   (~34 MB total)
  unsigned char* bp = (unsigned char*)d_ws;
  const size_t bp_sz = (size_t)Bn * (Sn - 1) * Ln;  // 33,521,664
  unsigned char* coal = bp + bp_sz;
  const size_t coal_sz = (size_t)Bn * Sn;           // 524,288
  int* last_tag = (int*)(coal + coal_sz);

  int* out = (int*)d_out;

  crf_forward<<<Bn, 64, 0, stream>>>(feat, Tm, bp, coal, last_tag);
  const int total = Bn * Sn;
  crf_backtrace<<<(total + 255) / 256, 256, 0, stream>>>(bp, coal, last_tag, out);
}

// Round 3
// 294.175 us; speedup vs baseline: 4.8367x; 1.2763x over previous
//
#include <hip/hip_runtime.h>

// Viterbi decode (LinearCRF): features [B,S,L] f32, transitions [L,L] f32 -> best_path [B,S] int32
// B=512, S=1024, L=64. One wave (64 lanes) per batch element; lane = tag j.
// Serial 1023-step recurrence -> wall time == per-step dependent-chain latency.
constexpr int Bn = 512;
constexpr int Sn = 1024;
constexpr int Ln = 64;

// ---- wave64 max reduction via DPP ----
#define DPPMAX(ctrl)                                                          \
  {                                                                           \
    int _xi = __float_as_int(x);                                              \
    int _yi = __builtin_amdgcn_update_dpp(_xi, _xi, ctrl, 0xf, 0xf, false);   \
    x = fmaxf(x, __int_as_float(_yi));                                        \
  }

__device__ __forceinline__ float wave_max64(float x) {
  DPPMAX(0x121)  // row_ror:1
  DPPMAX(0x122)  // row_ror:2
  DPPMAX(0x124)  // row_ror:4
  DPPMAX(0x128)  // row_ror:8
  DPPMAX(0x142)  // row_bcast15
  DPPMAX(0x143)  // row_bcast31 -> lane 63 holds wave max
  return __int_as_float(__builtin_amdgcn_readlane(__float_as_int(x), 63));
}

__device__ __forceinline__ float rdlane(float v, int lane) {
  return __int_as_float(__builtin_amdgcn_readlane(__float_as_int(v), lane));
}

// One Viterbi step. Exact arithmetic: scores are rnd(fv_i + T[i][j]), selection is
// strict-> in ascending candidate index == np.argmax first-index rule; candidates
// provably superset of possible column winners (margin Dspan + 0.01 >> fp slack).
#define CRF_STEP(T_, FEATC_)                                                     \
  do {                                                                           \
    const float M_ = wave_max64(fv);                                             \
    const float thr_ = M_ - DpE;                                                 \
    const unsigned long long cm_ = __ballot(fv >= thr_);                         \
    const int k_ = __popcll(cm_);                                                \
    unsigned char cv_;                                                           \
    if (__builtin_expect(k_ <= 2, 1)) {                                          \
      /* branchless: duplicate candidate when k==1 */                            \
      const int i0_ = __ffsll((long long)cm_) - 1;                               \
      const unsigned long long m1_ = cm_ & (cm_ - 1);                            \
      const int i1_ = (k_ > 1) ? (__ffsll((long long)m1_) - 1) : i0_;            \
      const float t0_ = sT[i0_ * Ln + j];                                        \
      const float t1_ = sT[i1_ * Ln + j];                                        \
      const float v0_ = rdlane(fv, i0_);                                         \
      const float v1_ = rdlane(fv, i1_);                                         \
      const float s0_ = v0_ + t0_;                                               \
      const float s1_ = v1_ + t1_;                                               \
      const bool tk_ = (k_ > 1) && (s1_ > s0_);                                  \
      const float best_ = tk_ ? s1_ : s0_;                                       \
      const int bx_ = tk_ ? i1_ : i0_;                                           \
      fv = (FEATC_) + best_;                                                     \
      bpb[(size_t)((T_) - 1) * Ln] = (unsigned char)bx_;                         \
      const int f0_ = __builtin_amdgcn_readfirstlane(bx_);                       \
      cv_ = (__ballot(bx_ == f0_) == ~0ull) ? (unsigned char)f0_                 \
                                            : (unsigned char)0xFF;               \
    } else {                                                                     \
      /* rare (k>2): dynamic loop over candidate bits, ascending index */        \
      unsigned long long m_ = cm_;                                               \
      int i_ = __ffsll((long long)m_) - 1;                                       \
      m_ &= m_ - 1;                                                              \
      float best_ = rdlane(fv, i_) + sT[i_ * Ln + j];                            \
      int bx_ = i_;                                                              \
      while (m_) {                                                               \
        i_ = __ffsll((long long)m_) - 1;                                         \
        m_ &= m_ - 1;                                                            \
        const float s_ = rdlane(fv, i_) + sT[i_ * Ln + j];                       \
        const bool tk_ = s_ > best_;                                             \
        best_ = tk_ ? s_ : best_;                                                \
        bx_ = tk_ ? i_ : bx_;                                                    \
      }                                                                          \
      fv = (FEATC_) + best_;                                                     \
      bpb[(size_t)((T_) - 1) * Ln] = (unsigned char)bx_;                         \
      const int f0_ = __builtin_amdgcn_readfirstlane(bx_);                       \
      cv_ = (__ballot(bx_ == f0_) == ~0ull) ? (unsigned char)f0_                 \
                                            : (unsigned char)0xFF;               \
    }                                                                            \
    if (j == 0) coalb[(T_)] = cv_;                                               \
  } while (0)

__global__ __launch_bounds__(64) void crf_forward(
    const float* __restrict__ feat,       // [B][S][L]
    const float* __restrict__ Tm,         // [L][L]
    unsigned char* __restrict__ bp,       // [B][S-1][L] backpointers
    unsigned char* __restrict__ coal,     // [B][S]: istar if step coalesced, else 0xFF
    int* __restrict__ last_tag)           // [B]
{
  const int b = blockIdx.x;
  const int j = threadIdx.x;  // tag index 0..63

  __shared__ __align__(16) float sT[Ln * Ln];  // transitions row-major

  // stage T, tracking global span
  float tmx = -1e30f, tmn = 1e30f;
#pragma unroll 8
  for (int i = 0; i < Ln; ++i) {
    const float v = Tm[i * Ln + j];
    sT[i * Ln + j] = v;
    tmx = fmaxf(tmx, v);
    tmn = fminf(tmn, v);
  }
  __syncthreads();
#pragma unroll
  for (int off = 32; off >= 1; off >>= 1) {
    tmx = fmaxf(tmx, __shfl_xor(tmx, off));
    tmn = fminf(tmn, __shfl_xor(tmn, off));
  }
  // fixed margin: Dspan + 0.01 covers all fp rounding (|fv| <= ~6e3 -> 2ulp ~ 1e-3)
  const float DpE = (tmx - tmn) + 0.01f;

  const float* fb = feat + ((size_t)b * Sn) * Ln + j;
  unsigned char* bpb = bp + ((size_t)b * (Sn - 1)) * Ln + j;
  unsigned char* coalb = coal + (size_t)b * Sn;

  // forward_var = features[b][0][:]; 8-deep software prefetch ring (static indices)
  float fv = fb[0];
  float pf[8];
#pragma unroll
  for (int u = 0; u < 8; ++u) pf[u] = fb[(size_t)(1 + u) * Ln];

  for (int tb = 1; tb <= Sn - 8; tb += 8) {
#pragma unroll
    for (int u = 0; u < 8; ++u) {
      const int t = tb + u;
      const float featc = pf[u];
      int tn = t + 8;
      if (tn > Sn - 1) tn = Sn - 1;
      pf[u] = fb[(size_t)tn * Ln];
      CRF_STEP(t, featc);
    }
  }
#pragma unroll
  for (int u = 0; u < 7; ++u) {
    const float featc = pf[u];
    CRF_STEP(1017 + u, featc);
  }

  // last_tag = first-index argmax of final forward_var
  const float Mf = wave_max64(fv);
  const unsigned long long mk = __ballot(fv == Mf);
  if (j == 0) last_tag[b] = __ffsll((long long)mk) - 1;
}

__global__ __launch_bounds__(256) void crf_backtrace(
    const unsigned char* __restrict__ bp, const unsigned char* __restrict__ coal,
    const int* __restrict__ last_tag, int* __restrict__ out)
{
  const int gid = blockIdx.x * blockDim.x + threadIdx.x;
  if (gid >= Bn * Sn) return;
  const int b = gid >> 10;       // / Sn
  const int t = gid & (Sn - 1);  // % Sn

  const unsigned char* cb = coal + (size_t)b * Sn;
  int tag = -1;
  int u = t;
  // walk forward to the nearest chain break (coalesced step or sequence end)
  while (u < Sn - 1) {
    const unsigned char c = cb[u + 1];
    if (c != 0xFF) { tag = c; break; }  // path[u] = istar of step u+1
    ++u;
  }
  if (u == Sn - 1) tag = last_tag[b];
  // walk back through non-coalesced steps applying stored backpointers
  const unsigned char* bpb = bp + (size_t)b * (Sn - 1) * Ln;
  for (; u > t; --u) tag = bpb[(size_t)(u - 1) * Ln + tag];
  out[gid] = tag;
}

extern "C" void kernel_launch(void* const* d_in, const int* in_sizes, int n_in,
                              void* d_out, int out_size, void* d_ws, size_t ws_size,
                              hipStream_t stream) {
  const float* feat = (const float*)d_in[0];
  const float* Tm = (const float*)d_in[1];

  // workspace layout: bp | coal | last_tag   (~34 MB total)
  unsigned char* bp = (unsigned char*)d_ws;
  const size_t bp_sz = (size_t)Bn * (Sn - 1) * Ln;  // 33,521,664
  unsigned char* coal = bp + bp_sz;
  const size_t coal_sz = (size_t)Bn * Sn;           // 524,288
  int* last_tag = (int*)(coal + coal_sz);

  int* out = (int*)d_out;

  crf_forward<<<Bn, 64, 0, stream>>>(feat, Tm, bp, coal, last_tag);
  const int total = Bn * Sn;
  crf_backtrace<<<(total + 255) / 256, 256, 0, stream>>>(bp, coal, last_tag, out);
}